// Round 1
// baseline (683.375 us; speedup 1.0000x reference)
//
#include <hip/hip_runtime.h>
#include <math.h>

// CPDist: B=8, T=128, D=1024, V=4096, R=16, H=2
// outputs: p_eval[8], norm_const[8]  (16 floats total)
//
// norm_const[b] = sum_r S[b][0][r]*S[b][1][r],  S[b][h][r] = sum_v exp(dot+bias)
// p_eval[b]    = sum_r E[b][0][r]*E[b][1][r],  E[b][h][r] = exp value at v=points[b][h]
//
// ws layout: S[8][2][16] floats at offset 0, E[8][2][16] at offset 256.

#define B_ 8
#define T_ 128
#define D_ 1024
#define V_ 4096
#define R_ 16
#define H_ 2

__global__ void init_ws_kernel(float* ws) {
    int i = threadIdx.x;
    if (i < 512) ws[i] = 0.0f;
}

// grid: 2048 blocks x 64 threads. block -> (pair = blk>>6 -> (h,r), vblock = blk&63)
// each wave processes 64 rows (v = vblock*64 .. +63), row = (h*V + v)*R + r.
__global__ __launch_bounds__(64, 2) void cpdist_main(
    const float* __restrict__ hid,    // B*T*D
    const float* __restrict__ W,      // (V*R*H) x D
    const float* __restrict__ bias,   // V*R*H
    const int*   __restrict__ points, // B*H (int32)
    float* __restrict__ ws)
{
    const int lane = threadIdx.x;          // 0..63
    const int blk  = blockIdx.x;           // 0..2047
    const int pair = blk >> 6;             // 0..31
    const int h    = pair >> 4;            // 0..1
    const int r    = pair & 15;            // 0..15
    const int v0   = (blk & 63) << 6;      // starting v, 64 rows per block

    // after the folded reduce, lane l holds the sum for b = bitrev3(l&7)
    const int myb = ((lane & 1) << 2) | (lane & 2) | ((lane >> 2) & 1);

    // h_last fragments in registers: hreg[b][j] = h_last[b][j*256 + lane*4 .. +3]
    float4 hreg[8][4];
#pragma unroll
    for (int b = 0; b < 8; ++b) {
        const float* hb = hid + ((size_t)b * T_ + (T_ - 1)) * D_;
#pragma unroll
        for (int j = 0; j < 4; ++j)
            hreg[b][j] = *reinterpret_cast<const float4*>(hb + j * 256 + lane * 4);
    }

    const int pv = points[myb * H_ + h];   // v selected by (myb, h)

    const size_t rowStride = (size_t)R_ * D_;               // floats between consecutive v
    const size_t row0 = ((size_t)h * V_ + v0) * R_ + r;
    const float* wp = W + row0 * D_;
    const float* bp = bias + row0;

    // prefetch first row
    float4 cur[4];
#pragma unroll
    for (int j = 0; j < 4; ++j)
        cur[j] = *reinterpret_cast<const float4*>(wp + j * 256 + lane * 4);

    float accS = 0.0f;

    for (int it = 0; it < 64; ++it) {
        const int v = v0 + it;

        // prefetch next row into nxt while computing cur
        float4 nxt[4];
        if (it < 63) {
            const float* wn = wp + rowStride;
#pragma unroll
            for (int j = 0; j < 4; ++j)
                nxt[j] = *reinterpret_cast<const float4*>(wn + j * 256 + lane * 4);
        }

        // partial dot products for all 8 batches (128 FMAs/lane)
        float p[8];
#pragma unroll
        for (int b = 0; b < 8; ++b) {
            float s = 0.0f;
#pragma unroll
            for (int j = 0; j < 4; ++j) {
                s = fmaf(cur[j].x, hreg[b][j].x, s);
                s = fmaf(cur[j].y, hreg[b][j].y, s);
                s = fmaf(cur[j].z, hreg[b][j].z, s);
                s = fmaf(cur[j].w, hreg[b][j].w, s);
            }
            p[b] = s;
        }

        // folded reduce: 8 values over 64 lanes -> lane l holds total for b=bitrev3(l&7)
        float t[4];
        {
            const bool hi = lane & 1;
#pragma unroll
            for (int i = 0; i < 4; ++i) {
                float send = hi ? p[i] : p[i + 4];
                float recv = __shfl_xor(send, 1);
                float keep = hi ? p[i + 4] : p[i];
                t[i] = keep + recv;
            }
        }
        float u[2];
        {
            const bool hi = lane & 2;
#pragma unroll
            for (int i = 0; i < 2; ++i) {
                float send = hi ? t[i] : t[i + 2];
                float recv = __shfl_xor(send, 2);
                float keep = hi ? t[i + 2] : t[i];
                u[i] = keep + recv;
            }
        }
        float wv;
        {
            const bool hi = lane & 4;
            float send = hi ? u[0] : u[1];
            float recv = __shfl_xor(send, 4);
            float keep = hi ? u[1] : u[0];
            wv = keep + recv;
        }
        wv += __shfl_xor(wv, 8);
        wv += __shfl_xor(wv, 16);
        wv += __shfl_xor(wv, 32);

        const float rowbias = bp[(size_t)it * R_];   // uniform scalar per row
        const float val = __expf(wv + rowbias);
        accS += val;   // lanes 8..63 accumulate duplicates; only lanes 0..7 are read

        if (lane < 8 && v == pv)
            ws[256 + (myb * H_ + h) * R_ + r] = val;  // E[b][h][r], written exactly once

        if (it < 63) {
#pragma unroll
            for (int j = 0; j < 4; ++j) cur[j] = nxt[j];
            wp += rowStride;
        }
    }

    if (lane < 8)
        atomicAdd(&ws[(myb * H_ + h) * R_ + r], accS);  // S[b][h][r]
}

// 128 threads: tid -> b = tid>>4, r = tid&15. Reduce over r within 16-lane groups.
__global__ void cpdist_finalize(const float* __restrict__ ws, float* __restrict__ out) {
    const int tid = threadIdx.x;
    const int b = tid >> 4;
    const int r = tid & 15;
    const float e0 = ws[256 + (b * 2 + 0) * 16 + r];
    const float e1 = ws[256 + (b * 2 + 1) * 16 + r];
    const float s0 = ws[(b * 2 + 0) * 16 + r];
    const float s1 = ws[(b * 2 + 1) * 16 + r];
    float pe = e0 * e1;
    float nc = s0 * s1;
#pragma unroll
    for (int m = 1; m < 16; m <<= 1) {
        pe += __shfl_xor(pe, m);
        nc += __shfl_xor(nc, m);
    }
    if (r == 0) {
        out[b] = pe;        // p_eval
        out[8 + b] = nc;    // norm_const
    }
}

extern "C" void kernel_launch(void* const* d_in, const int* in_sizes, int n_in,
                              void* d_out, int out_size, void* d_ws, size_t ws_size,
                              hipStream_t stream) {
    const float* hid    = (const float*)d_in[0];   // last_hidden_state
    const float* W      = (const float*)d_in[1];   // param_w
    const float* bias   = (const float*)d_in[2];   // param_b
    const int*   points = (const int*)d_in[3];     // points (int32)
    float* out = (float*)d_out;
    float* ws  = (float*)d_ws;

    hipLaunchKernelGGL(init_ws_kernel, dim3(1), dim3(512), 0, stream, ws);
    hipLaunchKernelGGL(cpdist_main, dim3(2048), dim3(64), 0, stream,
                       hid, W, bias, points, ws);
    hipLaunchKernelGGL(cpdist_finalize, dim3(1), dim3(128), 0, stream, ws, out);
}

// Round 2
// 680.661 us; speedup vs baseline: 1.0040x; 1.0040x over previous
//
#include <hip/hip_runtime.h>
#include <math.h>

// CPDist: B=8, T=128, D=1024, V=4096, R=16, H=2
// outputs: p_eval[8], norm_const[8]  (16 floats total)
//
// norm_const[b] = sum_r S[b][0][r]*S[b][1][r],  S[b][h][r] = sum_v exp(dot+bias)
// p_eval[b]    = sum_r E[b][0][r]*E[b][1][r],  E[b][h][r] = exp value at v=points[b][h]
//
// Roofline: param_w = 512 MB fp32 read once from HBM -> ~81 us at 6.3 TB/s.
// ws layout: S[8][2][16] floats at offset 0, E[8][2][16] at offset 256.

#define B_ 8
#define T_ 128
#define D_ 1024
#define V_ 4096
#define R_ 16
#define H_ 2

__global__ void init_ws_kernel(float* ws) {
    int i = threadIdx.x;
    if (i < 512) ws[i] = 0.0f;
}

// Folded reduce: 8 values over 64 lanes -> lane l holds total for b=bitrev3(l&7).
// ~11 shuffles instead of 24 for naive per-value butterfly.
__device__ __forceinline__ float folded_reduce8(const float* p, int lane) {
    float t[4];
    {
        const bool hi = lane & 1;
#pragma unroll
        for (int i = 0; i < 4; ++i) {
            float send = hi ? p[i] : p[i + 4];
            float recv = __shfl_xor(send, 1);
            float keep = hi ? p[i + 4] : p[i];
            t[i] = keep + recv;
        }
    }
    float u[2];
    {
        const bool hi = lane & 2;
#pragma unroll
        for (int i = 0; i < 2; ++i) {
            float send = hi ? t[i] : t[i + 2];
            float recv = __shfl_xor(send, 2);
            float keep = hi ? t[i + 2] : t[i];
            u[i] = keep + recv;
        }
    }
    float wv;
    {
        const bool hi = lane & 4;
        float send = hi ? u[0] : u[1];
        float recv = __shfl_xor(send, 4);
        float keep = hi ? u[1] : u[0];
        wv = keep + recv;
    }
    wv += __shfl_xor(wv, 8);
    wv += __shfl_xor(wv, 16);
    wv += __shfl_xor(wv, 32);
    return wv;
}

// grid: 2048 blocks x 64 threads. block -> (pair = blk>>6 -> (h,r), vblock = blk&63)
// each wave processes 64 rows (v = vblock*64 .. +63), row = (h*V + v)*R + r.
// 2-row software pipeline: 8 KB in flight per wave, vmcnt drain every 2 rows.
__global__ __launch_bounds__(64, 2) void cpdist_main(
    const float* __restrict__ hid,    // B*T*D
    const float* __restrict__ W,      // (V*R*H) x D
    const float* __restrict__ bias,   // V*R*H
    const int*   __restrict__ points, // B*H (int32)
    float* __restrict__ ws)
{
    const int lane = threadIdx.x;          // 0..63
    const int blk  = blockIdx.x;           // 0..2047
    const int pair = blk >> 6;             // 0..31
    const int h    = pair >> 4;            // 0..1
    const int r    = pair & 15;            // 0..15
    const int v0   = (blk & 63) << 6;      // starting v, 64 rows per block

    // after the folded reduce, lane l holds the sum for b = bitrev3(l&7)
    const int myb = ((lane & 1) << 2) | (lane & 2) | ((lane >> 2) & 1);

    // h_last fragments in registers: hreg[b][j] = h_last[b][j*256 + lane*4 .. +3]
    float4 hreg[8][4];
#pragma unroll
    for (int b = 0; b < 8; ++b) {
        const float* hb = hid + ((size_t)b * T_ + (T_ - 1)) * D_;
#pragma unroll
        for (int j = 0; j < 4; ++j)
            hreg[b][j] = *reinterpret_cast<const float4*>(hb + j * 256 + lane * 4);
    }

    const int pv = points[myb * H_ + h];   // v selected by (myb, h)

    const size_t rowStride = (size_t)R_ * D_;               // floats between consecutive v
    const size_t row0 = ((size_t)h * V_ + v0) * R_ + r;
    const float* wp = W + row0 * D_;
    const float* bp = bias + row0;

    // prefetch first 2 rows: cur[0..3] = row v0, cur[4..7] = row v0+1
    float4 cur[8];
#pragma unroll
    for (int j = 0; j < 4; ++j) {
        cur[j]     = *reinterpret_cast<const float4*>(wp + j * 256 + lane * 4);
        cur[4 + j] = *reinterpret_cast<const float4*>(wp + rowStride + j * 256 + lane * 4);
    }

    float accS = 0.0f;
    const int eidx = 256 + (myb * H_ + h) * R_ + r;

    for (int it = 0; it < 64; it += 2) {
        // prefetch rows it+2, it+3 while computing it, it+1
        float4 nxt[8];
        if (it < 62) {
            const float* wn = wp + 2 * rowStride;
#pragma unroll
            for (int j = 0; j < 4; ++j) {
                nxt[j]     = *reinterpret_cast<const float4*>(wn + j * 256 + lane * 4);
                nxt[4 + j] = *reinterpret_cast<const float4*>(wn + rowStride + j * 256 + lane * 4);
            }
        }

        const float biasA = bp[(size_t)it * R_];
        const float biasB = bp[(size_t)(it + 1) * R_];

        // row A (v0+it): partial dots for all 8 batches (128 FMAs/lane)
        float p[8];
#pragma unroll
        for (int b = 0; b < 8; ++b) {
            float s = 0.0f;
#pragma unroll
            for (int j = 0; j < 4; ++j) {
                s = fmaf(cur[j].x, hreg[b][j].x, s);
                s = fmaf(cur[j].y, hreg[b][j].y, s);
                s = fmaf(cur[j].z, hreg[b][j].z, s);
                s = fmaf(cur[j].w, hreg[b][j].w, s);
            }
            p[b] = s;
        }
        const float wvA = folded_reduce8(p, lane);

        // row B (v0+it+1)
#pragma unroll
        for (int b = 0; b < 8; ++b) {
            float s = 0.0f;
#pragma unroll
            for (int j = 0; j < 4; ++j) {
                s = fmaf(cur[4 + j].x, hreg[b][j].x, s);
                s = fmaf(cur[4 + j].y, hreg[b][j].y, s);
                s = fmaf(cur[4 + j].z, hreg[b][j].z, s);
                s = fmaf(cur[4 + j].w, hreg[b][j].w, s);
            }
            p[b] = s;
        }
        const float wvB = folded_reduce8(p, lane);

        const float valA = __expf(wvA + biasA);
        const float valB = __expf(wvB + biasB);
        accS += valA;   // same sequential order as before (bitwise-stable sum)
        accS += valB;

        if (lane < 8) {
            if (v0 + it == pv)     ws[eidx] = valA;  // E[b][h][r], written exactly once
            if (v0 + it + 1 == pv) ws[eidx] = valB;
        }

        if (it < 62) {
#pragma unroll
            for (int j = 0; j < 8; ++j) cur[j] = nxt[j];
            wp += 2 * rowStride;
        }
    }

    if (lane < 8)
        atomicAdd(&ws[(myb * H_ + h) * R_ + r], accS);  // S[b][h][r]
}

// 128 threads: tid -> b = tid>>4, r = tid&15. Reduce over r within 16-lane groups.
__global__ void cpdist_finalize(const float* __restrict__ ws, float* __restrict__ out) {
    const int tid = threadIdx.x;
    const int b = tid >> 4;
    const int r = tid & 15;
    const float e0 = ws[256 + (b * 2 + 0) * 16 + r];
    const float e1 = ws[256 + (b * 2 + 1) * 16 + r];
    const float s0 = ws[(b * 2 + 0) * 16 + r];
    const float s1 = ws[(b * 2 + 1) * 16 + r];
    float pe = e0 * e1;
    float nc = s0 * s1;
#pragma unroll
    for (int m = 1; m < 16; m <<= 1) {
        pe += __shfl_xor(pe, m);
        nc += __shfl_xor(nc, m);
    }
    if (r == 0) {
        out[b] = pe;        // p_eval
        out[8 + b] = nc;    // norm_const
    }
}

extern "C" void kernel_launch(void* const* d_in, const int* in_sizes, int n_in,
                              void* d_out, int out_size, void* d_ws, size_t ws_size,
                              hipStream_t stream) {
    const float* hid    = (const float*)d_in[0];   // last_hidden_state
    const float* W      = (const float*)d_in[1];   // param_w
    const float* bias   = (const float*)d_in[2];   // param_b
    const int*   points = (const int*)d_in[3];     // points (int32)
    float* out = (float*)d_out;
    float* ws  = (float*)d_ws;

    hipLaunchKernelGGL(init_ws_kernel, dim3(1), dim3(512), 0, stream, ws);
    hipLaunchKernelGGL(cpdist_main, dim3(2048), dim3(64), 0, stream,
                       hid, W, bias, points, ws);
    hipLaunchKernelGGL(cpdist_finalize, dim3(1), dim3(128), 0, stream, ws, out);
}

// Round 3
// 671.734 us; speedup vs baseline: 1.0173x; 1.0133x over previous
//
#include <hip/hip_runtime.h>
#include <math.h>

// CPDist: B=8, T=128, D=1024, V=4096, R=16, H=2
// outputs: p_eval[8], norm_const[8]  (16 floats total)
//
// norm_const[b] = sum_r S[b][0][r]*S[b][1][r],  S[b][h][r] = sum_v exp(dot+bias)
// p_eval[b]    = sum_r E[b][0][r]*E[b][1][r],  E[b][h][r] = exp value at v=points[b][h]
//
// Roofline: param_w = 512 MB fp32 read once from HBM -> ~82 us at 6.4 TB/s.
//
// ws layout (floats):
//   [0 .. 16384)          S_part[b][pair][vblock]  (b=8, pair=h*16+r=32, vblock=64)
//   [16384 .. 16640)      E[b][h][r]               (written unconditionally, unique writer)
// No zero-init needed anywhere -> no init kernel, no atomics.

#define B_ 8
#define T_ 128
#define D_ 1024
#define V_ 4096
#define R_ 16
#define H_ 2

// Folded reduce: 8 values over 64 lanes -> lane l holds total for b=bitrev3(l&7).
__device__ __forceinline__ float folded_reduce8(const float* p, int lane) {
    float t[4];
    {
        const bool hi = lane & 1;
#pragma unroll
        for (int i = 0; i < 4; ++i) {
            float send = hi ? p[i] : p[i + 4];
            float recv = __shfl_xor(send, 1);
            float keep = hi ? p[i + 4] : p[i];
            t[i] = keep + recv;
        }
    }
    float u[2];
    {
        const bool hi = lane & 2;
#pragma unroll
        for (int i = 0; i < 2; ++i) {
            float send = hi ? t[i] : t[i + 2];
            float recv = __shfl_xor(send, 2);
            float keep = hi ? t[i + 2] : t[i];
            u[i] = keep + recv;
        }
    }
    float wv;
    {
        const bool hi = lane & 4;
        float send = hi ? u[0] : u[1];
        float recv = __shfl_xor(send, 4);
        float keep = hi ? u[1] : u[0];
        wv = keep + recv;
    }
    wv += __shfl_xor(wv, 8);
    wv += __shfl_xor(wv, 16);
    wv += __shfl_xor(wv, 32);
    return wv;
}

// grid: 2048 blocks x 64 threads. block -> (pair = blk>>6 -> (h,r), vblock = blk&63)
// Each wave processes 64 rows. Ping-pong register buffers A/B, NO copies:
// compute(A) -> reissue(A) -> compute(B) -> reissue(B). The compiler's
// per-register waitcnt then waits on only 4 loads (vmcnt(4)-style), never
// draining to zero -- the other buffer's loads stay in flight across every wait.
__global__ __launch_bounds__(64, 2) void cpdist_main(
    const float* __restrict__ hid,    // B*T*D
    const float* __restrict__ W,      // (V*R*H) x D
    const float* __restrict__ bias,   // V*R*H
    const int*   __restrict__ points, // B*H
    float* __restrict__ ws)
{
    const int lane = threadIdx.x;          // 0..63
    const int blk  = blockIdx.x;           // 0..2047
    const int pair = blk >> 6;             // 0..31
    const int h    = pair >> 4;            // 0..1
    const int r    = pair & 15;            // 0..15
    const int vblk = blk & 63;
    const int v0   = vblk << 6;            // starting v, 64 rows per block

    // after the folded reduce, lane l holds the sum for b = bitrev3(l&7)
    const int myb = ((lane & 1) << 2) | (lane & 2) | ((lane >> 2) & 1);

    // h_last fragments in registers: hreg[b][j] = h_last[b][j*256 + lane*4 .. +3]
    float4 hreg[8][4];
#pragma unroll
    for (int b = 0; b < 8; ++b) {
        const float* hb = hid + ((size_t)b * T_ + (T_ - 1)) * D_;
#pragma unroll
        for (int j = 0; j < 4; ++j)
            hreg[b][j] = *reinterpret_cast<const float4*>(hb + j * 256 + lane * 4);
    }

    const int pv = points[myb * H_ + h];   // v selected by (myb, h)

    const size_t rowStride = (size_t)R_ * D_;               // floats between consecutive v
    const size_t row0 = ((size_t)h * V_ + v0) * R_ + r;
    const float* wp = W + row0 * D_;
    const float* bp = bias + row0;

    // preload rows 0 (A) and 1 (B)
    float4 A[4], Bf[4];
#pragma unroll
    for (int j = 0; j < 4; ++j) {
        A[j]  = *reinterpret_cast<const float4*>(wp + j * 256 + lane * 4);
        Bf[j] = *reinterpret_cast<const float4*>(wp + rowStride + j * 256 + lane * 4);
    }

    float accS = 0.0f;
    const int eidx = 16384 + (myb * H_ + h) * R_ + r;

    for (int it = 0; it < 64; it += 2) {
        const float biasA = bp[(size_t)it * R_];
        const float biasB = bp[(size_t)(it + 1) * R_];

        // ---- compute row it from A (waits only on A's 4 loads) ----
        float p[8];
#pragma unroll
        for (int b = 0; b < 8; ++b) {
            float s = 0.0f;
#pragma unroll
            for (int j = 0; j < 4; ++j) {
                s = fmaf(A[j].x, hreg[b][j].x, s);
                s = fmaf(A[j].y, hreg[b][j].y, s);
                s = fmaf(A[j].z, hreg[b][j].z, s);
                s = fmaf(A[j].w, hreg[b][j].w, s);
            }
            p[b] = s;
        }
        const float wvA = folded_reduce8(p, lane);

        // reissue A <- row it+2 (B's loads + these stay in flight)
        if (it < 62) {
            const float* wn = wp + (size_t)(it + 2) * rowStride;
#pragma unroll
            for (int j = 0; j < 4; ++j)
                A[j] = *reinterpret_cast<const float4*>(wn + j * 256 + lane * 4);
        }

        // ---- compute row it+1 from B (waits only on B's 4 loads) ----
#pragma unroll
        for (int b = 0; b < 8; ++b) {
            float s = 0.0f;
#pragma unroll
            for (int j = 0; j < 4; ++j) {
                s = fmaf(Bf[j].x, hreg[b][j].x, s);
                s = fmaf(Bf[j].y, hreg[b][j].y, s);
                s = fmaf(Bf[j].z, hreg[b][j].z, s);
                s = fmaf(Bf[j].w, hreg[b][j].w, s);
            }
            p[b] = s;
        }
        const float wvB = folded_reduce8(p, lane);

        // reissue B <- row it+3
        if (it < 62) {
            const float* wn = wp + (size_t)(it + 3) * rowStride;
#pragma unroll
            for (int j = 0; j < 4; ++j)
                Bf[j] = *reinterpret_cast<const float4*>(wn + j * 256 + lane * 4);
        }

        const float valA = __expf(wvA + biasA);
        const float valB = __expf(wvB + biasB);
        accS += valA;
        accS += valB;

        if (lane < 8) {
            if (v0 + it == pv)     ws[eidx] = valA;  // unique writer per E slot
            if (v0 + it + 1 == pv) ws[eidx] = valB;
        }
    }

    // partial S: block-private slot, no atomics, no init needed
    if (lane < 8)
        ws[myb * 2048 + pair * 64 + vblk] = accS;
}

// 256 threads: t -> b = t>>5, h = (t>>4)&1, r = t&15.
// Sum 64 vblock partials (contiguous, float4), combine h-halves via shuffle,
// reduce over r via shuffle.
__global__ void cpdist_finalize(const float* __restrict__ ws, float* __restrict__ out) {
    const int t = threadIdx.x;
    const int b = t >> 5;
    const int h = (t >> 4) & 1;
    const int r = t & 15;
    const int pair = h * 16 + r;

    const float* sp = ws + b * 2048 + pair * 64;
    float S = 0.0f;
#pragma unroll
    for (int i = 0; i < 16; ++i) {
        const float4 v4 = *reinterpret_cast<const float4*>(sp + i * 4);
        S += v4.x + v4.y + v4.z + v4.w;
    }
    const float E = ws[16384 + (b * 2 + h) * 16 + r];

    const float So = __shfl_xor(S, 16);
    const float Eo = __shfl_xor(E, 16);
    float nc = S * So;   // S[b][0][r] * S[b][1][r] (both h-lanes compute it)
    float pe = E * Eo;
#pragma unroll
    for (int m = 1; m < 16; m <<= 1) {
        nc += __shfl_xor(nc, m);
        pe += __shfl_xor(pe, m);
    }
    if ((t & 31) == 0) {
        out[b] = pe;        // p_eval
        out[8 + b] = nc;    // norm_const
    }
}

extern "C" void kernel_launch(void* const* d_in, const int* in_sizes, int n_in,
                              void* d_out, int out_size, void* d_ws, size_t ws_size,
                              hipStream_t stream) {
    const float* hid    = (const float*)d_in[0];   // last_hidden_state
    const float* W      = (const float*)d_in[1];   // param_w
    const float* bias   = (const float*)d_in[2];   // param_b
    const int*   points = (const int*)d_in[3];     // points
    float* out = (float*)d_out;
    float* ws  = (float*)d_ws;

    hipLaunchKernelGGL(cpdist_main, dim3(2048), dim3(64), 0, stream,
                       hid, W, bias, points, ws);
    hipLaunchKernelGGL(cpdist_finalize, dim3(1), dim3(256), 0, stream, ws, out);
}